// Round 10
// baseline (459.020 us; speedup 1.0000x reference)
//
#include <hip/hip_runtime.h>

// Problem constants
#define S_TOK 4096
#define D_DIM 4096
#define O_DIM 4096
#define R_DIM 256
#define E_EXP 8
#define NTOK  8192   // B*S
#define KSPLIT 4

typedef __bf16 bf16x8 __attribute__((ext_vector_type(8)));
typedef float  f32x4  __attribute__((ext_vector_type(4)));

__device__ __forceinline__ unsigned short f2bf(float f) {
  unsigned int u = __float_as_uint(f);
  u += 0x7FFFu + ((u >> 16) & 1u);   // RNE (no NaN in data)
  return (unsigned short)(u >> 16);
}
__device__ __forceinline__ float bf2f(unsigned short h) {
  return __uint_as_float(((unsigned int)h) << 16);
}

__device__ __forceinline__ void gload_lds16(const unsigned short* g, unsigned short* l) {
  __builtin_amdgcn_global_load_lds((const __attribute__((address_space(1))) void*)g,
                                   (__attribute__((address_space(3))) void*)l, 16, 0, 0);
}

// Fused counted-wait + barrier as ONE volatile asm with memory clobber.
#define PIPE_FENCE(N)                                                        \
  do {                                                                       \
    asm volatile("s_waitcnt vmcnt(" #N ")\n\ts_barrier" ::: "memory");       \
    __builtin_amdgcn_sched_barrier(0);                                       \
  } while (0)
#define LGKMC(N)                                                             \
  do {                                                                       \
    asm volatile("s_waitcnt lgkmcnt(" #N ")" ::: "memory");                  \
    __builtin_amdgcn_sched_barrier(0);                                       \
  } while (0)
#define SBAR0 __builtin_amdgcn_sched_barrier(0)

// ============ merged prologue: casts + transposes in one launch ============
// blocks [0,16384):   X16  = bf16(x)        (33.5M elems, 8/thread)
// blocks [16384,24576): W16 = bf16(wb)      (16.7M elems)
// blocks [24576,32768): A16t[e][256][4096] = bf16(la[e][4096][256])^T
// blocks [32768,40960): B16t[e][4096][256] = bf16(lb[e][256][4096])^T
__global__ void prologue(const float* __restrict__ x, const float* __restrict__ wb,
                         const float* __restrict__ la, const float* __restrict__ lb,
                         unsigned short* __restrict__ X16, unsigned short* __restrict__ W16,
                         unsigned short* __restrict__ A16t, unsigned short* __restrict__ B16t) {
  __shared__ unsigned short tile[32][33];
  const int b = blockIdx.x, t = threadIdx.x;
  if (b < 24576) {
    const float* in  = (b < 16384) ? x : wb;
    unsigned short* out = (b < 16384) ? X16 : W16;
    size_t g = (size_t)((b < 16384) ? b : (b - 16384)) * 256 + t;
    const float4* i4 = (const float4*)in;
    float4 a = i4[g * 2], c = i4[g * 2 + 1];
    union { unsigned short h[8]; int4 v; } u;
    u.h[0] = f2bf(a.x); u.h[1] = f2bf(a.y); u.h[2] = f2bf(a.z); u.h[3] = f2bf(a.w);
    u.h[4] = f2bf(c.x); u.h[5] = f2bf(c.y); u.h[6] = f2bf(c.z); u.h[7] = f2bf(c.w);
    ((int4*)out)[g] = u.v;
    return;
  }
  // transpose sections: in[e][P][Q] -> out[e][Q][P]
  const float* in; unsigned short* out; int P, Q, pt, qt, e;
  if (b < 32768) {
    int b2 = b - 24576; e = b2 >> 10; int rem = b2 & 1023;
    in = la; out = A16t; P = D_DIM; Q = R_DIM;
    pt = (rem >> 3) * 32; qt = (rem & 7) * 32;
  } else {
    int b3 = b - 32768; e = b3 >> 10; int rem = b3 & 1023;
    in = lb; out = B16t; P = R_DIM; Q = D_DIM;
    pt = (rem & 7) * 32; qt = (rem >> 3) * 32;
  }
  const float* ie = in + (size_t)e * P * Q;
  unsigned short* oe = out + (size_t)e * P * Q;
  int tx = t & 31, ty = t >> 5;
  #pragma unroll
  for (int i = 0; i < 32; i += 8) {
    int p = pt + ty + i, q = qt + tx;
    tile[ty + i][tx] = f2bf(ie[(size_t)p * Q + q]);
  }
  __syncthreads();
  #pragma unroll
  for (int i = 0; i < 32; i += 8) {
    int q = qt + ty + i, p = pt + tx;
    oe[(size_t)q * P + p] = tile[tx][ty + i];
  }
}

// ------------- deterministic stable counting sort of tokens by expert -------------
__global__ void sort_tokens(const int* __restrict__ tt, int* __restrict__ token_perm,
                            int* __restrict__ inv_perm,
                            int* __restrict__ tile_e, int* __restrict__ tile_j0,
                            int* __restrict__ tile_jend, int* __restrict__ ntiles_out) {
  __shared__ int ltt[S_TOK];
  __shared__ int lc[256 * 8];
  __shared__ int basee[8], cnte[8];
  __shared__ int ssl[S_TOK];
  int t = threadIdx.x;
  for (int s = t; s < S_TOK; s += 256) ltt[s] = tt[s];
  __syncthreads();
  int c[8] = {0,0,0,0,0,0,0,0};
  #pragma unroll
  for (int i = 0; i < 16; i++) { int e = ltt[t * 16 + i]; c[e]++; }
  #pragma unroll
  for (int e = 0; e < 8; e++) lc[t * 8 + e] = c[e];
  __syncthreads();
  if (t < 8) {
    int run = 0;
    for (int q = 0; q < 256; q++) { int tmp = lc[q * 8 + t]; lc[q * 8 + t] = run; run += tmp; }
    cnte[t] = run;
  }
  __syncthreads();
  if (t == 0) { int tot = 0; for (int e = 0; e < 8; e++) { basee[e] = tot; tot += cnte[e]; } }
  __syncthreads();
  int off[8];
  #pragma unroll
  for (int e = 0; e < 8; e++) off[e] = basee[e] + lc[t * 8 + e];
  #pragma unroll
  for (int i = 0; i < 16; i++) { int s = t * 16 + i; int e = ltt[s]; ssl[off[e]++] = s; }
  __syncthreads();
  for (int j = t; j < NTOK; j += 256) {
    int row = ((j & 1) << 12) + ssl[j >> 1];
    token_perm[j] = row;
    inv_perm[row] = j;
  }
  if (t == 0) {
    int nt = 0;
    for (int e = 0; e < 8; e++) {
      int js = 2 * basee[e], je = js + 2 * cnte[e];
      for (int j0 = js; j0 < je; j0 += 128) {
        tile_e[nt] = e; tile_j0[nt] = j0;
        tile_jend[nt] = (je < j0 + 128) ? je : (j0 + 128);
        nt++;
      }
    }
    *ntiles_out = nt;
  }
}

// ===================== 256x256 read-ahead dense GEMM (FROZEN from R9) ==============
template<int FUSED>
__global__ __launch_bounds__(512, 2) void gemm256_dense(
    const unsigned short* __restrict__ A, const unsigned short* __restrict__ B,
    float* __restrict__ C, const unsigned short* __restrict__ lout,
    const int* __restrict__ invp) {
  __shared__ __align__(16) unsigned short ldsA[2][2][8192];
  __shared__ __align__(16) unsigned short ldsB[2][2][8192];
  int b = blockIdx.x;
  int xc = b & 7, q = b >> 3;
  const int bm = (xc >> 1) * 8 + (q >> 3);   // 0..31
  const int bn = (xc & 1) * 8 + (q & 7);     // 0..15
  const int tid = threadIdx.x, l = tid & 63, w = tid >> 6;
  const int wm = w >> 2, wn = w & 3;

  const unsigned short *srcA0, *srcA1, *srcB0, *srcB1;
  {
    int i0 = tid, r0 = i0 >> 2;
    int c0 = ((i0 & 3) * 16) ^ (((r0 >> 1) & 3) << 4);
    srcA0 = A + (size_t)(bm * 256 + r0) * 4096 + (c0 >> 1);
    srcB0 = B + (size_t)(bn * 256 + r0) * 4096 + (c0 >> 1);
    int i1 = 512 + tid, r1 = i1 >> 2;
    int c1 = ((i1 & 3) * 16) ^ (((r1 >> 1) & 3) << 4);
    srcA1 = A + (size_t)(bm * 256 + r1) * 4096 + (c1 >> 1);
    srcB1 = B + (size_t)(bn * 256 + r1) * 4096 + (c1 >> 1);
  }
  const int d0 = tid * 8;

  const int lane15 = l & 15, kb16 = (l >> 4) * 16;
  int offA[8], offB[4];
  #pragma unroll
  for (int m = 0; m < 8; m++) {
    int r = wm * 128 + m * 16 + lane15;
    offA[m] = r * 64 + (kb16 ^ (((r >> 1) & 3) << 4));
  }
  #pragma unroll
  for (int n = 0; n < 4; n++) {
    int r = wn * 64 + n * 16 + lane15;
    offB[n] = r * 64 + (kb16 ^ (((r >> 1) & 3) << 4));
  }

  f32x4 acc[8][4];
  #pragma unroll
  for (int m = 0; m < 8; m++)
    #pragma unroll
    for (int n = 0; n < 4; n++) acc[m][n] = (f32x4){0.f, 0.f, 0.f, 0.f};

  bf16x8 Ab0[4], Ab1[4], Bb0[4], Bb1[4];

#define STAGE_A(tt, kh) do { int _o = (tt) * 64 + (kh) * 32;                  \
    gload_lds16(srcA0 + _o, &ldsA[(tt) & 1][kh][d0]);                         \
    gload_lds16(srcA1 + _o, &ldsA[(tt) & 1][kh][d0 + 4096]); } while (0)
#define STAGE_B(tt, kh) do { int _o = (tt) * 64 + (kh) * 32;                  \
    gload_lds16(srcB0 + _o, &ldsB[(tt) & 1][kh][d0]);                         \
    gload_lds16(srcB1 + _o, &ldsB[(tt) & 1][kh][d0 + 4096]); } while (0)
#define RD_A(RING, QQ, KS, BUF) do {                                          \
    const char* _s = (const char*)&ldsA[RING][KS][0];                         \
    BUF[0] = *(const bf16x8*)(_s + offA[(QQ) * 4 + 0]);                       \
    BUF[1] = *(const bf16x8*)(_s + offA[(QQ) * 4 + 1]);                       \
    BUF[2] = *(const bf16x8*)(_s + offA[(QQ) * 4 + 2]);                       \
    BUF[3] = *(const bf16x8*)(_s + offA[(QQ) * 4 + 3]); } while (0)
#define RD_B(RING, KS, BUF) do {                                              \
    const char* _s = (const char*)&ldsB[RING][KS][0];                         \
    BUF[0] = *(const bf16x8*)(_s + offB[0]);                                  \
    BUF[1] = *(const bf16x8*)(_s + offB[1]);                                  \
    BUF[2] = *(const bf16x8*)(_s + offB[2]);                                  \
    BUF[3] = *(const bf16x8*)(_s + offB[3]); } while (0)
#define PRIO_MFMA(Q, AB, BB) do {                                             \
    __builtin_amdgcn_s_setprio(1);                                            \
    _Pragma("unroll")                                                         \
    for (int mm = 0; mm < 4; mm++)                                            \
      _Pragma("unroll")                                                       \
      for (int nn = 0; nn < 4; nn++)                                          \
        acc[(Q) * 4 + mm][nn] = __builtin_amdgcn_mfma_f32_16x16x32_bf16(      \
            AB[mm], BB[nn], acc[(Q) * 4 + mm][nn], 0, 0, 0);                  \
    __builtin_amdgcn_s_setprio(0); } while (0)

  STAGE_A(0, 0); STAGE_B(0, 0); STAGE_A(0, 1); STAGE_B(0, 1);
  STAGE_A(1, 0); STAGE_B(1, 0);
  PIPE_FENCE(4);
  RD_B(0, 0, Bb0); RD_A(0, 0, 0, Ab0);
  SBAR0;

  #pragma unroll 1
  for (int t = 0; t < 62; ++t) {
    const int r = t & 1, nr = r ^ 1;
    RD_A(r, 1, 0, Ab1); SBAR0; STAGE_A(t + 1, 1); SBAR0; LGKMC(4);
    PRIO_MFMA(0, Ab0, Bb0);
    RD_B(r, 1, Bb1); RD_A(r, 0, 1, Ab0); SBAR0; STAGE_B(t + 1, 1); SBAR0; LGKMC(8);
    PRIO_MFMA(1, Ab1, Bb0);
    PIPE_FENCE(4);
    RD_A(r, 1, 1, Ab1); SBAR0; STAGE_A(t + 2, 0); SBAR0; LGKMC(4);
    PRIO_MFMA(0, Ab0, Bb1);
    RD_B(nr, 0, Bb0); RD_A(nr, 0, 0, Ab0); SBAR0; STAGE_B(t + 2, 0); SBAR0; LGKMC(8);
    PRIO_MFMA(1, Ab1, Bb1);
    PIPE_FENCE(4);
  }
  RD_A(0, 1, 0, Ab1); SBAR0; STAGE_A(63, 1); SBAR0; LGKMC(4); PRIO_MFMA(0, Ab0, Bb0);
  RD_B(0, 1, Bb1); RD_A(0, 0, 1, Ab0); SBAR0; STAGE_B(63, 1); SBAR0; LGKMC(8);
  PRIO_MFMA(1, Ab1, Bb0); PIPE_FENCE(4);
  RD_A(0, 1, 1, Ab1); SBAR0; LGKMC(4); PRIO_MFMA(0, Ab0, Bb1);
  RD_B(1, 0, Bb0); RD_A(1, 0, 0, Ab0); SBAR0; LGKMC(8); PRIO_MFMA(1, Ab1, Bb1);
  PIPE_FENCE(0);
  RD_A(1, 1, 0, Ab1); SBAR0; LGKMC(4); PRIO_MFMA(0, Ab0, Bb0);
  RD_B(1, 1, Bb1); RD_A(1, 0, 1, Ab0); SBAR0; LGKMC(8); PRIO_MFMA(1, Ab1, Bb0);
  RD_A(1, 1, 1, Ab1); SBAR0; LGKMC(4); PRIO_MFMA(0, Ab0, Bb1);
  LGKMC(0); PRIO_MFMA(1, Ab1, Bb1);

#undef STAGE_A
#undef STAGE_B
#undef RD_A
#undef RD_B
#undef PRIO_MFMA

  const int rowbase = bm * 256 + wm * 128;
  const int colbase = bn * 256 + wn * 64;
  #pragma unroll
  for (int m = 0; m < 8; m++)
    #pragma unroll
    for (int v = 0; v < 4; v++) {
      int rrow = rowbase + m * 16 + (l >> 4) * 4 + v;
      float lv0 = 0.f, lv1 = 0.f, lv2 = 0.f, lv3 = 0.f;
      if (FUSED) {
        int jr = invp[rrow];
        const unsigned short* lr = lout + (size_t)jr * O_DIM + colbase + lane15;
        lv0 = bf2f(lr[0]); lv1 = bf2f(lr[16]); lv2 = bf2f(lr[32]); lv3 = bf2f(lr[48]);
      }
      size_t base = (size_t)rrow * O_DIM + colbase + lane15;
      C[base]      = acc[m][0][v] + lv0;
      C[base + 16] = acc[m][1][v] + lv1;
      C[base + 32] = acc[m][2][v] + lv2;
      C[base + 48] = acc[m][3][v] + lv3;
    }
}

// ======= NEW: pipelined 128x128 LoRA GEMM (R4 structure @128^2 + swizzle) =======
// 4 waves (2x2, wave tile 64x64), BK=32, 4-ring LDS (64KB -> 2 blocks/CU),
// stage 3 tiles ahead, one fused vmcnt(8)+barrier per K-tile, 8->4->0 tail drain.
// Zero-conflict XOR swizzle (inverse-swizzled global source + swizzled ds_read)
// -- R1 measured 3.35e7 conflicts on the unswizzled [*][32] layout (8-way).
// MODE 1: outU[kc][j][r] = bf16 partial( X[perm[j]] @ A16t[e]^T ), K-chunk kc
// MODE 3: outU[j]        = bf16( 2 * H16s @ B16t[e]^T )  (pure write, sorted rows)
template<int MODE>
__global__ __launch_bounds__(256, 2) void gemm_nt(
    const unsigned short* __restrict__ Aop, const unsigned short* __restrict__ Bop,
    unsigned short* __restrict__ outU,
    const int* __restrict__ perm, const int* __restrict__ tile_e,
    const int* __restrict__ tile_j0, const int* __restrict__ tile_jend,
    const int* __restrict__ ntiles, int K) {
  int bm = blockIdx.x, bn = blockIdx.y;
  if (bm >= *ntiles) return;
  int e = tile_e[bm], j0 = tile_j0[bm], jend = tile_jend[bm];
  const int kc = (MODE == 1) ? blockIdx.z : 0;
  const int t = threadIdx.x, l = t & 63, w = t >> 6;
  const int wm = w >> 1, wn = w & 1;
  __shared__ __align__(16) unsigned short ldsA[4][4096];  // ring: 128 rows x 32 elems
  __shared__ __align__(16) unsigned short ldsB[4][4096];

  // staging sources: chunk idx = ck*256+t; row = idx>>2; 16B col (idx&3)*16,
  // XOR-swizzled by ((row>>1)&3)<<4 bytes (inverse-swizzle on global source).
  const unsigned short *sA0, *sA1, *sB0, *sB1;
  {
    int i0 = t, r0 = i0 >> 2;
    int c0 = ((i0 & 3) * 16) ^ (((r0 >> 1) & 3) << 4);
    int i1 = 256 + t, r1 = i1 >> 2;
    int c1 = ((i1 & 3) * 16) ^ (((r1 >> 1) & 3) << 4);
    int ja = j0 + r0; if (ja > jend - 1) ja = jend - 1;
    int jb = j0 + r1; if (jb > jend - 1) jb = jend - 1;
    int g0 = (MODE == 1) ? perm[ja] : ja;
    int g1 = (MODE == 1) ? perm[jb] : jb;
    sA0 = Aop + (size_t)g0 * K + kc * 1024 + (c0 >> 1);
    sA1 = Aop + (size_t)g1 * K + kc * 1024 + (c1 >> 1);
    const unsigned short* bp = Bop + ((MODE == 1) ? (size_t)e * R_DIM * D_DIM
                                                  : (size_t)e * O_DIM * R_DIM);
    sB0 = bp + (size_t)(bn * 128 + r0) * K + kc * 1024 + (c0 >> 1);
    sB1 = bp + (size_t)(bn * 128 + r1) * K + kc * 1024 + (c1 >> 1);
  }
  const int d0 = t * 8;

  const int lane15 = l & 15, kb16 = (l >> 4) * 16;
  int offA[4], offB[4];
  #pragma unroll
  for (int m = 0; m < 4; m++) {
    int r = wm * 64 + m * 16 + lane15;
    offA[m] = r * 64 + (kb16 ^ (((r >> 1) & 3) << 4));
  }
  #pragma unroll
  for (int n = 0; n < 4; n++) {
    int r = wn * 64 + n * 16 + lane15;
    offB[n] = r * 64 + (kb16 ^ (((r >> 1) & 3) << 4));
  }

  f32x4 acc[4][4];
  #pragma unroll
  for (int m = 0; m < 4; m++)
    #pragma unroll
    for (int n = 0; n < 4; n++) acc[m][n] = (f32x4){0.f, 0.f, 0.f, 0.f};

  auto stage = [&](int tt) {
    const int ring = tt & 3;
    const int go = tt * 32;
    gload_lds16(sA0 + go, &ldsA[ring][d0]);
    gload_lds16(sA1 + go, &ldsA[ring][d0 + 2048]);
    gload_lds16(sB0 + go, &ldsB[ring][d0]);
    gload_lds16(sB1 + go, &ldsB[ring][d0 + 2048]);
  };

  auto body = [&](int ring) {
    const char* bA = (const char*)&ldsA[ring][0];
    const char* bB = (const char*)&ldsB[ring][0];
    bf16x8 a[4], bb[4];
    #pragma unroll
    for (int m = 0; m < 4; m++) a[m] = *(const bf16x8*)(bA + offA[m]);
    #pragma unroll
    for (int n = 0; n < 4; n++) bb[n] = *(const bf16x8*)(bB + offB[n]);
    __builtin_amdgcn_s_setprio(1);
    #pragma unroll
    for (int m = 0; m < 4; m++)
      #pragma unroll
      for (int n = 0; n < 4; n++)
        acc[m][n] = __builtin_amdgcn_mfma_f32_16x16x32_bf16(a[m], bb[n], acc[m][n], 0, 0, 0);
    __builtin_amdgcn_s_setprio(0);
  };

  const int nk = (MODE == 1) ? 32 : (K / 32);   // MODE3: K=256 -> 8
  stage(0); stage(1); stage(2);
  PIPE_FENCE(8);                 // stage(0) landed (4 oldest of 12)
  #pragma unroll 1
  for (int kt = 0; kt < nk - 3; ++kt) {
    stage(kt + 3);
    body(kt & 3);
    PIPE_FENCE(8);               // stage(kt+1) landed; kt+2, kt+3 in flight
  }
  body((nk - 3) & 3);
  PIPE_FENCE(4);                 // stage(nk-2) landed
  body((nk - 2) & 3);
  PIPE_FENCE(0);                 // stage(nk-1) landed
  body((nk - 1) & 3);

  const int rowbase = j0 + wm * 64;
  const int colbase = bn * 128 + wn * 64;
  #pragma unroll
  for (int m = 0; m < 4; m++) {
    #pragma unroll
    for (int n = 0; n < 4; n++) {
      #pragma unroll
      for (int v = 0; v < 4; v++) {
        int r = rowbase + m * 16 + (l >> 4) * 4 + v;
        int cc = colbase + n * 16 + lane15;
        if (r < jend) {
          if (MODE == 1) {
            outU[(size_t)kc * (NTOK * R_DIM) + (size_t)r * R_DIM + cc] = f2bf(acc[m][n][v]);
          } else {
            outU[(size_t)r * O_DIM + cc] = f2bf(2.0f * acc[m][n][v]);
          }
        }
      }
    }
  }
}

// ---------------- reduce bf16 split-K partials -> bf16 H16s ----------------
__global__ void reduce_h(const unsigned short* __restrict__ hp, unsigned short* __restrict__ h16) {
  size_t g = (size_t)blockIdx.x * 256 + threadIdx.x;   // 8-elem group
  float s[8] = {0,0,0,0,0,0,0,0};
  #pragma unroll
  for (int c = 0; c < KSPLIT; c++) {
    int4 v = ((const int4*)hp)[g + (size_t)c * (NTOK * R_DIM / 8)];
    const unsigned short* us = (const unsigned short*)&v;
    #pragma unroll
    for (int i = 0; i < 8; i++) s[i] += bf2f(us[i]);
  }
  union { unsigned short h[8]; int4 v; } u;
  #pragma unroll
  for (int i = 0; i < 8; i++) u.h[i] = f2bf(s[i]);
  ((int4*)h16)[g] = u.v;
}

// ---------------- workspace layout (bytes) ----------------
#define X16_OFF   ((size_t)0)             // 67108864
#define W16_OFF   ((size_t)67108864)      // 33554432
#define A16T_OFF  ((size_t)100663296)     // 16777216
#define B16T_OFF  ((size_t)117440512)     // 16777216
#define H16S_OFF  ((size_t)134217728)     // 4194304
#define PERM_OFF  ((size_t)138412032)     // 32768
#define INVP_OFF  ((size_t)138444800)     // 32768
#define TILEE_OFF ((size_t)138477568)     // 512
#define TILEJ0_OFF ((size_t)138478080)
#define TILEJE_OFF ((size_t)138478592)
#define NT_OFF    ((size_t)138479104)
#define HP16_OFF  ((size_t)138479616)     // 16777216
#define LOUT_OFF  ((size_t)155256832)     // 67108864
#define WS_NEED   ((size_t)222365696)

extern "C" void kernel_launch(void* const* d_in, const int* in_sizes, int n_in,
                              void* d_out, int out_size, void* d_ws, size_t ws_size,
                              hipStream_t stream) {
  const float* x  = (const float*)d_in[0];
  const float* wb = (const float*)d_in[1];
  const float* la = (const float*)d_in[2];
  const float* lb = (const float*)d_in[3];
  const int* tok  = (const int*)d_in[4];
  float* out = (float*)d_out;

  char* ws = (char*)d_ws;
  unsigned short* X16  = (unsigned short*)(ws + X16_OFF);
  unsigned short* W16  = (unsigned short*)(ws + W16_OFF);
  unsigned short* A16t = (unsigned short*)(ws + A16T_OFF);
  unsigned short* B16t = (unsigned short*)(ws + B16T_OFF);
  unsigned short* H16s = (unsigned short*)(ws + H16S_OFF);
  unsigned short* HP16 = (unsigned short*)(ws + HP16_OFF);
  unsigned short* LOUT = (unsigned short*)(ws + LOUT_OFF);
  int* perm  = (int*)(ws + PERM_OFF);
  int* invp  = (int*)(ws + INVP_OFF);
  int* tl_e  = (int*)(ws + TILEE_OFF);
  int* tl_j0 = (int*)(ws + TILEJ0_OFF);
  int* tl_je = (int*)(ws + TILEJE_OFF);
  int* nt    = (int*)(ws + NT_OFF);

  // casts + transposes merged into one launch
  prologue<<<40960, 256, 0, stream>>>(x, wb, la, lb, X16, W16, A16t, B16t);
  sort_tokens<<<1, 256, 0, stream>>>(tok, perm, invp, tl_e, tl_j0, tl_je, nt);

  // LoRA: H partials -> H16s -> LOUT (pure write, sorted rows)
  gemm_nt<1><<<dim3(71, 2, KSPLIT), 256, 0, stream>>>(X16, A16t, HP16,
                                                      perm, tl_e, tl_j0, tl_je, nt, D_DIM);
  reduce_h<<<1024, 256, 0, stream>>>(HP16, H16s);
  gemm_nt<3><<<dim3(71, 32), 256, 0, stream>>>(H16s, B16t, LOUT,
                                               perm, tl_e, tl_j0, tl_je, nt, R_DIM);
  // dense + fused LoRA add
  gemm256_dense<1><<<512, 512, 0, stream>>>(X16, W16, out, LOUT, invp);
}

// Round 11
// 458.737 us; speedup vs baseline: 1.0006x; 1.0006x over previous
//
#include <hip/hip_runtime.h>

// Problem constants
#define S_TOK 4096
#define D_DIM 4096
#define O_DIM 4096
#define R_DIM 256
#define E_EXP 8
#define NTOK  8192   // B*S
#define KSPLIT 4

typedef __bf16 bf16x8 __attribute__((ext_vector_type(8)));
typedef float  f32x4  __attribute__((ext_vector_type(4)));

__device__ __forceinline__ unsigned short f2bf(float f) {
  unsigned int u = __float_as_uint(f);
  u += 0x7FFFu + ((u >> 16) & 1u);   // RNE (no NaN in data)
  return (unsigned short)(u >> 16);
}
__device__ __forceinline__ float bf2f(unsigned short h) {
  return __uint_as_float(((unsigned int)h) << 16);
}

__device__ __forceinline__ void gload_lds16(const unsigned short* g, unsigned short* l) {
  __builtin_amdgcn_global_load_lds((const __attribute__((address_space(1))) void*)g,
                                   (__attribute__((address_space(3))) void*)l, 16, 0, 0);
}

// Fused counted-wait + barrier as ONE volatile asm with memory clobber.
#define PIPE_FENCE(N)                                                        \
  do {                                                                       \
    asm volatile("s_waitcnt vmcnt(" #N ")\n\ts_barrier" ::: "memory");       \
    __builtin_amdgcn_sched_barrier(0);                                       \
  } while (0)

// ============ merged prologue: casts + transposes + token sort, one launch ============
// blocks [0,16384):     X16 = bf16(x)
// blocks [16384,24576): W16 = bf16(wb)
// blocks [24576,32768): A16t[e][256][4096] = bf16(la[e][4096][256])^T
// blocks [32768,40960): B16t[e][4096][256] = bf16(lb[e][256][4096])^T
// block  40960:         deterministic stable counting sort of tokens by expert
__global__ void prologue(const float* __restrict__ x, const float* __restrict__ wb,
                         const float* __restrict__ la, const float* __restrict__ lb,
                         unsigned short* __restrict__ X16, unsigned short* __restrict__ W16,
                         unsigned short* __restrict__ A16t, unsigned short* __restrict__ B16t,
                         const int* __restrict__ tt, int* __restrict__ token_perm,
                         int* __restrict__ inv_perm, int* __restrict__ tile_e,
                         int* __restrict__ tile_j0, int* __restrict__ tile_jend,
                         int* __restrict__ ntiles_out) {
  __shared__ int sm[10256];   // 41 KB pool: sort arrays / transpose tile (aliased)
  const int b = blockIdx.x, t = threadIdx.x;
  if (b >= 40960) {
    // ---- token sort (1 block) ----
    int* ltt   = sm;            // 4096
    int* lc    = sm + 4096;     // 2048
    int* ssl   = sm + 6144;     // 4096
    int* basee = sm + 10240;    // 8
    int* cnte  = sm + 10248;    // 8
    for (int s = t; s < S_TOK; s += 256) ltt[s] = tt[s];
    __syncthreads();
    int c[8] = {0,0,0,0,0,0,0,0};
    #pragma unroll
    for (int i = 0; i < 16; i++) { int e = ltt[t * 16 + i]; c[e]++; }
    #pragma unroll
    for (int e = 0; e < 8; e++) lc[t * 8 + e] = c[e];
    __syncthreads();
    if (t < 8) {
      int run = 0;
      for (int qq = 0; qq < 256; qq++) { int tmp = lc[qq * 8 + t]; lc[qq * 8 + t] = run; run += tmp; }
      cnte[t] = run;
    }
    __syncthreads();
    if (t == 0) { int tot = 0; for (int e = 0; e < 8; e++) { basee[e] = tot; tot += cnte[e]; } }
    __syncthreads();
    int off[8];
    #pragma unroll
    for (int e = 0; e < 8; e++) off[e] = basee[e] + lc[t * 8 + e];
    #pragma unroll
    for (int i = 0; i < 16; i++) { int s = t * 16 + i; int e = ltt[s]; ssl[off[e]++] = s; }
    __syncthreads();
    for (int j = t; j < NTOK; j += 256) {
      int row = ((j & 1) << 12) + ssl[j >> 1];
      token_perm[j] = row;
      inv_perm[row] = j;
    }
    if (t == 0) {
      int nt = 0;
      for (int e = 0; e < 8; e++) {
        int js = 2 * basee[e], je = js + 2 * cnte[e];
        for (int j0 = js; j0 < je; j0 += 128) {
          tile_e[nt] = e; tile_j0[nt] = j0;
          tile_jend[nt] = (je < j0 + 128) ? je : (j0 + 128);
          nt++;
        }
      }
      *ntiles_out = nt;
    }
    return;
  }
  if (b < 24576) {
    const float* in  = (b < 16384) ? x : wb;
    unsigned short* out = (b < 16384) ? X16 : W16;
    size_t g = (size_t)((b < 16384) ? b : (b - 16384)) * 256 + t;
    const float4* i4 = (const float4*)in;
    float4 a = i4[g * 2], c = i4[g * 2 + 1];
    union { unsigned short h[8]; int4 v; } u;
    u.h[0] = f2bf(a.x); u.h[1] = f2bf(a.y); u.h[2] = f2bf(a.z); u.h[3] = f2bf(a.w);
    u.h[4] = f2bf(c.x); u.h[5] = f2bf(c.y); u.h[6] = f2bf(c.z); u.h[7] = f2bf(c.w);
    ((int4*)out)[g] = u.v;
    return;
  }
  // transpose sections: in[e][P][Q] -> out[e][Q][P]
  unsigned short (*tile)[33] = (unsigned short (*)[33])sm;
  const float* in; unsigned short* out; int P, Q, pt, qt, e;
  if (b < 32768) {
    int b2 = b - 24576; e = b2 >> 10; int rem = b2 & 1023;
    in = la; out = A16t; P = D_DIM; Q = R_DIM;
    pt = (rem >> 3) * 32; qt = (rem & 7) * 32;
  } else {
    int b3 = b - 32768; e = b3 >> 10; int rem = b3 & 1023;
    in = lb; out = B16t; P = R_DIM; Q = D_DIM;
    pt = (rem & 7) * 32; qt = (rem >> 3) * 32;
  }
  const float* ie = in + (size_t)e * P * Q;
  unsigned short* oe = out + (size_t)e * P * Q;
  int tx = t & 31, ty = t >> 5;
  #pragma unroll
  for (int i = 0; i < 32; i += 8) {
    int p = pt + ty + i, q = qt + tx;
    tile[ty + i][tx] = f2bf(ie[(size_t)p * Q + q]);
  }
  __syncthreads();
  #pragma unroll
  for (int i = 0; i < 32; i += 8) {
    int q = qt + ty + i, p = pt + tx;
    oe[(size_t)q * P + p] = tile[tx][ty + i];
  }
}

// ===================== 256x256 read-ahead dense GEMM =====================
// R9 skeleton (verified) with explicit LGKMC/sched_barrier pins REMOVED:
// the compiler emits its own counted lgkmcnt for ds_read->MFMA deps (m97),
// and hand pins only constrain it (m141). PIPE_FENCE (vmcnt+barrier in one
// asm w/ memory clobber) is unchanged -- it carries all cross-wave ordering.
template<int FUSED>
__global__ __launch_bounds__(512, 2) void gemm256_dense(
    const unsigned short* __restrict__ A, const unsigned short* __restrict__ B,
    float* __restrict__ C, const unsigned short* __restrict__ lout,
    const int* __restrict__ invp) {
  __shared__ __align__(16) unsigned short ldsA[2][2][8192];
  __shared__ __align__(16) unsigned short ldsB[2][2][8192];
  int b = blockIdx.x;
  int xc = b & 7, q = b >> 3;
  const int bm = (xc >> 1) * 8 + (q >> 3);   // 0..31
  const int bn = (xc & 1) * 8 + (q & 7);     // 0..15
  const int tid = threadIdx.x, l = tid & 63, w = tid >> 6;
  const int wm = w >> 2, wn = w & 3;

  const unsigned short *srcA0, *srcA1, *srcB0, *srcB1;
  {
    int i0 = tid, r0 = i0 >> 2;
    int c0 = ((i0 & 3) * 16) ^ (((r0 >> 1) & 3) << 4);
    srcA0 = A + (size_t)(bm * 256 + r0) * 4096 + (c0 >> 1);
    srcB0 = B + (size_t)(bn * 256 + r0) * 4096 + (c0 >> 1);
    int i1 = 512 + tid, r1 = i1 >> 2;
    int c1 = ((i1 & 3) * 16) ^ (((r1 >> 1) & 3) << 4);
    srcA1 = A + (size_t)(bm * 256 + r1) * 4096 + (c1 >> 1);
    srcB1 = B + (size_t)(bn * 256 + r1) * 4096 + (c1 >> 1);
  }
  const int d0 = tid * 8;

  const int lane15 = l & 15, kb16 = (l >> 4) * 16;
  int offA[8], offB[4];
  #pragma unroll
  for (int m = 0; m < 8; m++) {
    int r = wm * 128 + m * 16 + lane15;
    offA[m] = r * 64 + (kb16 ^ (((r >> 1) & 3) << 4));
  }
  #pragma unroll
  for (int n = 0; n < 4; n++) {
    int r = wn * 64 + n * 16 + lane15;
    offB[n] = r * 64 + (kb16 ^ (((r >> 1) & 3) << 4));
  }

  f32x4 acc[8][4];
  #pragma unroll
  for (int m = 0; m < 8; m++)
    #pragma unroll
    for (int n = 0; n < 4; n++) acc[m][n] = (f32x4){0.f, 0.f, 0.f, 0.f};

  bf16x8 Ab0[4], Ab1[4], Bb0[4], Bb1[4];

#define STAGE_A(tt, kh) do { int _o = (tt) * 64 + (kh) * 32;                  \
    gload_lds16(srcA0 + _o, &ldsA[(tt) & 1][kh][d0]);                         \
    gload_lds16(srcA1 + _o, &ldsA[(tt) & 1][kh][d0 + 4096]); } while (0)
#define STAGE_B(tt, kh) do { int _o = (tt) * 64 + (kh) * 32;                  \
    gload_lds16(srcB0 + _o, &ldsB[(tt) & 1][kh][d0]);                         \
    gload_lds16(srcB1 + _o, &ldsB[(tt) & 1][kh][d0 + 4096]); } while (0)
#define RD_A(RING, QQ, KS, BUF) do {                                          \
    const char* _s = (const char*)&ldsA[RING][KS][0];                         \
    BUF[0] = *(const bf16x8*)(_s + offA[(QQ) * 4 + 0]);                       \
    BUF[1] = *(const bf16x8*)(_s + offA[(QQ) * 4 + 1]);                       \
    BUF[2] = *(const bf16x8*)(_s + offA[(QQ) * 4 + 2]);                       \
    BUF[3] = *(const bf16x8*)(_s + offA[(QQ) * 4 + 3]); } while (0)
#define RD_B(RING, KS, BUF) do {                                              \
    const char* _s = (const char*)&ldsB[RING][KS][0];                         \
    BUF[0] = *(const bf16x8*)(_s + offB[0]);                                  \
    BUF[1] = *(const bf16x8*)(_s + offB[1]);                                  \
    BUF[2] = *(const bf16x8*)(_s + offB[2]);                                  \
    BUF[3] = *(const bf16x8*)(_s + offB[3]); } while (0)
#define PRIO_MFMA(Q, AB, BB) do {                                             \
    __builtin_amdgcn_s_setprio(1);                                            \
    _Pragma("unroll")                                                         \
    for (int mm = 0; mm < 4; mm++)                                            \
      _Pragma("unroll")                                                       \
      for (int nn = 0; nn < 4; nn++)                                          \
        acc[(Q) * 4 + mm][nn] = __builtin_amdgcn_mfma_f32_16x16x32_bf16(      \
            AB[mm], BB[nn], acc[(Q) * 4 + mm][nn], 0, 0, 0);                  \
    __builtin_amdgcn_s_setprio(0); } while (0)

  // prologue: A0k0,B0k0,A0k1,B0k1,A1k0,B1k0 (12 loads); vmcnt(4) -> oldest 8 landed
  STAGE_A(0, 0); STAGE_B(0, 0); STAGE_A(0, 1); STAGE_B(0, 1);
  STAGE_A(1, 0); STAGE_B(1, 0);
  PIPE_FENCE(4);
  RD_B(0, 0, Bb0); RD_A(0, 0, 0, Ab0);

  // steady: tiles 0..61 (fences only at ph1/ph3; compiler handles lgkm deps)
  #pragma unroll 1
  for (int t = 0; t < 62; ++t) {
    const int r = t & 1, nr = r ^ 1;
    RD_A(r, 1, 0, Ab1); STAGE_A(t + 1, 1);
    PRIO_MFMA(0, Ab0, Bb0);
    RD_B(r, 1, Bb1); RD_A(r, 0, 1, Ab0); STAGE_B(t + 1, 1);
    PRIO_MFMA(1, Ab1, Bb0);
    PIPE_FENCE(4);
    RD_A(r, 1, 1, Ab1); STAGE_A(t + 2, 0);
    PRIO_MFMA(0, Ab0, Bb1);
    RD_B(nr, 0, Bb0); RD_A(nr, 0, 0, Ab0); STAGE_B(t + 2, 0);
    PRIO_MFMA(1, Ab1, Bb1);
    PIPE_FENCE(4);
  }
  // tile 62 (r=0): stages only k1(63); F3 drains to 0
  RD_A(0, 1, 0, Ab1); STAGE_A(63, 1); PRIO_MFMA(0, Ab0, Bb0);
  RD_B(0, 1, Bb1); RD_A(0, 0, 1, Ab0); STAGE_B(63, 1); PRIO_MFMA(1, Ab1, Bb0);
  PIPE_FENCE(4);
  RD_A(0, 1, 1, Ab1); PRIO_MFMA(0, Ab0, Bb1);
  RD_B(1, 0, Bb0); RD_A(1, 0, 0, Ab0); PRIO_MFMA(1, Ab1, Bb1);
  PIPE_FENCE(0);
  // tile 63 (r=1): no stages, no fences
  RD_A(1, 1, 0, Ab1); PRIO_MFMA(0, Ab0, Bb0);
  RD_B(1, 1, Bb1); RD_A(1, 0, 1, Ab0); PRIO_MFMA(1, Ab1, Bb0);
  RD_A(1, 1, 1, Ab1); PRIO_MFMA(0, Ab0, Bb1);
  PRIO_MFMA(1, Ab1, Bb1);

#undef STAGE_A
#undef STAGE_B
#undef RD_A
#undef RD_B
#undef PRIO_MFMA

  const int rowbase = bm * 256 + wm * 128;
  const int colbase = bn * 256 + wn * 64;
  #pragma unroll
  for (int m = 0; m < 8; m++)
    #pragma unroll
    for (int v = 0; v < 4; v++) {
      int rrow = rowbase + m * 16 + (l >> 4) * 4 + v;
      float lv0 = 0.f, lv1 = 0.f, lv2 = 0.f, lv3 = 0.f;
      if (FUSED) {
        int jr = invp[rrow];
        const unsigned short* lr = lout + (size_t)jr * O_DIM + colbase + lane15;
        lv0 = bf2f(lr[0]); lv1 = bf2f(lr[16]); lv2 = bf2f(lr[32]); lv3 = bf2f(lr[48]);
      }
      size_t base = (size_t)rrow * O_DIM + colbase + lane15;
      C[base]      = acc[m][0][v] + lv0;
      C[base + 16] = acc[m][1][v] + lv1;
      C[base + 32] = acc[m][2][v] + lv2;
      C[base + 48] = acc[m][3][v] + lv3;
    }
}

// ======= pipelined 128x128 LoRA GEMM (unchanged from R10, passed) =======
template<int MODE>
__global__ __launch_bounds__(256, 2) void gemm_nt(
    const unsigned short* __restrict__ Aop, const unsigned short* __restrict__ Bop,
    unsigned short* __restrict__ outU,
    const int* __restrict__ perm, const int* __restrict__ tile_e,
    const int* __restrict__ tile_j0, const int* __restrict__ tile_jend,
    const int* __restrict__ ntiles, int K) {
  int bm = blockIdx.x, bn = blockIdx.y;
  if (bm >= *ntiles) return;
  int e = tile_e[bm], j0 = tile_j0[bm], jend = tile_jend[bm];
  const int kc = (MODE == 1) ? blockIdx.z : 0;
  const int t = threadIdx.x, l = t & 63, w = t >> 6;
  const int wm = w >> 1, wn = w & 1;
  __shared__ __align__(16) unsigned short ldsA[4][4096];
  __shared__ __align__(16) unsigned short ldsB[4][4096];

  const unsigned short *sA0, *sA1, *sB0, *sB1;
  {
    int i0 = t, r0 = i0 >> 2;
    int c0 = ((i0 & 3) * 16) ^ (((r0 >> 1) & 3) << 4);
    int i1 = 256 + t, r1 = i1 >> 2;
    int c1 = ((i1 & 3) * 16) ^ (((r1 >> 1) & 3) << 4);
    int ja = j0 + r0; if (ja > jend - 1) ja = jend - 1;
    int jb = j0 + r1; if (jb > jend - 1) jb = jend - 1;
    int g0 = (MODE == 1) ? perm[ja] : ja;
    int g1 = (MODE == 1) ? perm[jb] : jb;
    sA0 = Aop + (size_t)g0 * K + kc * 1024 + (c0 >> 1);
    sA1 = Aop + (size_t)g1 * K + kc * 1024 + (c1 >> 1);
    const unsigned short* bp = Bop + ((MODE == 1) ? (size_t)e * R_DIM * D_DIM
                                                  : (size_t)e * O_DIM * R_DIM);
    sB0 = bp + (size_t)(bn * 128 + r0) * K + kc * 1024 + (c0 >> 1);
    sB1 = bp + (size_t)(bn * 128 + r1) * K + kc * 1024 + (c1 >> 1);
  }
  const int d0 = t * 8;

  const int lane15 = l & 15, kb16 = (l >> 4) * 16;
  int offA[4], offB[4];
  #pragma unroll
  for (int m = 0; m < 4; m++) {
    int r = wm * 64 + m * 16 + lane15;
    offA[m] = r * 64 + (kb16 ^ (((r >> 1) & 3) << 4));
  }
  #pragma unroll
  for (int n = 0; n < 4; n++) {
    int r = wn * 64 + n * 16 + lane15;
    offB[n] = r * 64 + (kb16 ^ (((r >> 1) & 3) << 4));
  }

  f32x4 acc[4][4];
  #pragma unroll
  for (int m = 0; m < 4; m++)
    #pragma unroll
    for (int n = 0; n < 4; n++) acc[m][n] = (f32x4){0.f, 0.f, 0.f, 0.f};

  auto stage = [&](int tt) {
    const int ring = tt & 3;
    const int go = tt * 32;
    gload_lds16(sA0 + go, &ldsA[ring][d0]);
    gload_lds16(sA1 + go, &ldsA[ring][d0 + 2048]);
    gload_lds16(sB0 + go, &ldsB[ring][d0]);
    gload_lds16(sB1 + go, &ldsB[ring][d0 + 2048]);
  };

  auto body = [&](int ring) {
    const char* bA = (const char*)&ldsA[ring][0];
    const char* bB = (const char*)&ldsB[ring][0];
    bf16x8 a[4], bb[4];
    #pragma unroll
    for (int m = 0; m < 4; m++) a[m] = *(const bf16x8*)(bA + offA[m]);
    #pragma unroll
    for (int n = 0; n < 4; n++) bb[n] = *(const bf16x8*)(bB + offB[n]);
    __builtin_amdgcn_s_setprio(1);
    #pragma unroll
    for (int m = 0; m < 4; m++)
      #pragma unroll
      for (int n = 0; n < 4; n++)
        acc[m][n] = __builtin_amdgcn_mfma_f32_16x16x32_bf16(a[m], bb[n], acc[m][n], 0, 0, 0);
    __builtin_amdgcn_s_setprio(0);
  };

  const int nk = (MODE == 1) ? 32 : (K / 32);
  stage(0); stage(1); stage(2);
  PIPE_FENCE(8);
  #pragma unroll 1
  for (int kt = 0; kt < nk - 3; ++kt) {
    stage(kt + 3);
    body(kt & 3);
    PIPE_FENCE(8);
  }
  body((nk - 3) & 3);
  PIPE_FENCE(4);
  body((nk - 2) & 3);
  PIPE_FENCE(0);
  body((nk - 1) & 3);

  const int rowbase = j0 + wm * 64;
  const int colbase = bn * 128 + wn * 64;
  #pragma unroll
  for (int m = 0; m < 4; m++) {
    #pragma unroll
    for (int n = 0; n < 4; n++) {
      #pragma unroll
      for (int v = 0; v < 4; v++) {
        int r = rowbase + m * 16 + (l >> 4) * 4 + v;
        int cc = colbase + n * 16 + lane15;
        if (r < jend) {
          if (MODE == 1) {
            outU[(size_t)kc * (NTOK * R_DIM) + (size_t)r * R_DIM + cc] = f2bf(acc[m][n][v]);
          } else {
            outU[(size_t)r * O_DIM + cc] = f2bf(2.0f * acc[m][n][v]);
          }
        }
      }
    }
  }
}

// ---------------- reduce bf16 split-K partials -> bf16 H16s ----------------
__global__ void reduce_h(const unsigned short* __restrict__ hp, unsigned short* __restrict__ h16) {
  size_t g = (size_t)blockIdx.x * 256 + threadIdx.x;
  float s[8] = {0,0,0,0,0,0,0,0};
  #pragma unroll
  for (int c = 0; c < KSPLIT; c++) {
    int4 v = ((const int4*)hp)[g + (size_t)c * (NTOK * R_DIM / 8)];
    const unsigned short* us = (const unsigned short*)&v;
    #pragma unroll
    for (int i = 0; i < 8; i++) s[i] += bf2f(us[i]);
  }
  union { unsigned short h[8]; int4 v; } u;
  #pragma unroll
  for (int i = 0; i < 8; i++) u.h[i] = f2bf(s[i]);
  ((int4*)h16)[g] = u.v;
}

// ---------------- workspace layout (bytes) ----------------
#define X16_OFF   ((size_t)0)             // 67108864
#define W16_OFF   ((size_t)67108864)      // 33554432
#define A16T_OFF  ((size_t)100663296)     // 16777216
#define B16T_OFF  ((size_t)117440512)     // 16777216
#define H16S_OFF  ((size_t)134217728)     // 4194304
#define PERM_OFF  ((size_t)138412032)     // 32768
#define INVP_OFF  ((size_t)138444800)     // 32768
#define TILEE_OFF ((size_t)138477568)     // 512
#define TILEJ0_OFF ((size_t)138478080)
#define TILEJE_OFF ((size_t)138478592)
#define NT_OFF    ((size_t)138479104)
#define HP16_OFF  ((size_t)138479616)     // 16777216
#define LOUT_OFF  ((size_t)155256832)     // 67108864

extern "C" void kernel_launch(void* const* d_in, const int* in_sizes, int n_in,
                              void* d_out, int out_size, void* d_ws, size_t ws_size,
                              hipStream_t stream) {
  const float* x  = (const float*)d_in[0];
  const float* wb = (const float*)d_in[1];
  const float* la = (const float*)d_in[2];
  const float* lb = (const float*)d_in[3];
  const int* tok  = (const int*)d_in[4];
  float* out = (float*)d_out;

  char* ws = (char*)d_ws;
  unsigned short* X16  = (unsigned short*)(ws + X16_OFF);
  unsigned short* W16  = (unsigned short*)(ws + W16_OFF);
  unsigned short* A16t = (unsigned short*)(ws + A16T_OFF);
  unsigned short* B16t = (unsigned short*)(ws + B16T_OFF);
  unsigned short* H16s = (unsigned short*)(ws + H16S_OFF);
  unsigned short* HP16 = (unsigned short*)(ws + HP16_OFF);
  unsigned short* LOUT = (unsigned short*)(ws + LOUT_OFF);
  int* perm  = (int*)(ws + PERM_OFF);
  int* invp  = (int*)(ws + INVP_OFF);
  int* tl_e  = (int*)(ws + TILEE_OFF);
  int* tl_j0 = (int*)(ws + TILEJ0_OFF);
  int* tl_je = (int*)(ws + TILEJE_OFF);
  int* nt    = (int*)(ws + NT_OFF);

  // casts + transposes + token sort in one launch
  prologue<<<40961, 256, 0, stream>>>(x, wb, la, lb, X16, W16, A16t, B16t,
                                      tok, perm, invp, tl_e, tl_j0, tl_je, nt);

  // LoRA: H partials -> H16s -> LOUT (pure write, sorted rows)
  gemm_nt<1><<<dim3(71, 2, KSPLIT), 256, 0, stream>>>(X16, A16t, HP16,
                                                      perm, tl_e, tl_j0, tl_je, nt, D_DIM);
  reduce_h<<<1024, 256, 0, stream>>>(HP16, H16s);
  gemm_nt<3><<<dim3(71, 32), 256, 0, stream>>>(H16s, B16t, LOUT,
                                               perm, tl_e, tl_j0, tl_je, nt, R_DIM);
  // dense + fused LoRA add
  gemm256_dense<1><<<512, 512, 0, stream>>>(X16, W16, out, LOUT, invp);
}